// Round 14
// baseline (499.383 us; speedup 1.0000x reference)
//
#include <hip/hip_runtime.h>

#define N_NODES 100000
#define N_EDGES 1600000
#define EPSV 1e-5f

__device__ __forceinline__ ushort f2bf(float f) {
  unsigned u = __float_as_uint(f);
  unsigned r = (u + 0x7FFFu + ((u >> 16) & 1u)) >> 16;
  return (ushort)r;
}

// ---------------- edge bucketize (one pass) + CSR build (XCD-affine) ----------------

#define FILL_SUB 256
#define GRP_W 12500
#define BUCKET_CAP 210000  // per-group capacity; E[count]=200K, sigma~420

// One pass over edges: partition into 8 XCD-group buckets of packed (dst, w|src).
// Block-local LDS counting -> 1 global atomicAdd per group per block -> dense writes.
__global__ __launch_bounds__(256) void bucket_kernel(const int* __restrict__ ei,
                                                     const float* __restrict__ ew,
                                                     int* __restrict__ bcur,
                                                     unsigned long long* __restrict__ bkt) {
  __shared__ int lcnt[8];
  __shared__ int lbase[8];
  const int tid = threadIdx.x;
  if (tid < 8) lcnt[tid] = 0;
  __syncthreads();
  int d[7];
  unsigned pay[7];
  int g[7];
  const int base_t = blockIdx.x * 256 + tid;
  const int STRIDE = 1024 * 256;
#pragma unroll
  for (int it = 0; it < 7; ++it) {
    int e = base_t + it * STRIDE;
    if (e < N_EDGES) {
      d[it] = __builtin_nontemporal_load(ei + N_EDGES + e);
      int src = __builtin_nontemporal_load(ei + e);
      float w = __builtin_nontemporal_load(ew + e);
      pay[it] = ((unsigned)f2bf(w) << 17) | (unsigned)src;
      g[it] = d[it] / GRP_W;
      atomicAdd(&lcnt[g[it]], 1);
    } else {
      g[it] = -1;
    }
  }
  __syncthreads();
  if (tid < 8) lbase[tid] = atomicAdd(&bcur[tid * 16], lcnt[tid]);
  __syncthreads();
  if (tid < 8) lcnt[tid] = 0;  // reuse as local cursor
  __syncthreads();
#pragma unroll
  for (int it = 0; it < 7; ++it) {
    if (g[it] >= 0) {
      int off = atomicAdd(&lcnt[g[it]], 1);
      bkt[(size_t)g[it] * BUCKET_CAP + lbase[g[it]] + off] =
          ((unsigned long long)pay[it] << 32) | (unsigned)(unsigned)d[it];
    }
  }
}

// XCD-affine histogram over the group's bucket only
__global__ void hist_kernel(const unsigned long long* __restrict__ bkt,
                            const int* __restrict__ bcur, int* __restrict__ cnt) {
  const int g = blockIdx.x & 7;
  const int sub = blockIdx.x >> 3;
  const int total = bcur[g * 16];
  const unsigned long long* b = bkt + (size_t)g * BUCKET_CAP;
  for (int i = sub * 256 + (int)threadIdx.x; i < total; i += FILL_SUB * 256) {
    unsigned long long ev = __builtin_nontemporal_load(b + i);
    atomicAdd(&cnt[(unsigned)ev], 1);
  }
}

#define SCAN_BLK 1024
#define SCAN_NB ((N_NODES + SCAN_BLK - 1) / SCAN_BLK)  // 98

__global__ void scan_phase1(const int* __restrict__ cnt, int* __restrict__ blocksum) {
  __shared__ int part[256];
  int base = blockIdx.x * SCAN_BLK + threadIdx.x * 4;
  int s = 0;
#pragma unroll
  for (int i = 0; i < 4; ++i) {
    int idx = base + i;
    if (idx < N_NODES) s += cnt[idx];
  }
  part[threadIdx.x] = s;
  __syncthreads();
  for (int d = 128; d > 0; d >>= 1) {
    if (threadIdx.x < d) part[threadIdx.x] += part[threadIdx.x + d];
    __syncthreads();
  }
  if (threadIdx.x == 0) blocksum[blockIdx.x] = part[0];
}

__global__ void scan_phase2(int* __restrict__ blocksum, int* __restrict__ rowptr) {
  __shared__ int part[128];
  int tid = threadIdx.x;
  int v = (tid < SCAN_NB) ? blocksum[tid] : 0;
  part[tid] = v;
  __syncthreads();
  for (int d = 1; d < 128; d <<= 1) {
    int t = (tid >= d) ? part[tid - d] : 0;
    __syncthreads();
    part[tid] += t;
    __syncthreads();
  }
  if (tid < SCAN_NB) blocksum[tid] = part[tid] - v;  // exclusive
  if (tid == 127) rowptr[N_NODES] = part[127];
}

__global__ void scan_phase3(const int* __restrict__ cnt, const int* __restrict__ blocksum,
                            int* __restrict__ rowptr, int* __restrict__ cursor) {
  __shared__ int part[256];
  int base = blockIdx.x * SCAN_BLK + threadIdx.x * 4;
  int c[4];
  int s = 0;
#pragma unroll
  for (int i = 0; i < 4; ++i) {
    int idx = base + i;
    c[i] = (idx < N_NODES) ? cnt[idx] : 0;
    s += c[i];
  }
  part[threadIdx.x] = s;
  __syncthreads();
  int me = s;
  for (int d = 1; d < 256; d <<= 1) {
    int t = (threadIdx.x >= d) ? part[threadIdx.x - d] : 0;
    __syncthreads();
    part[threadIdx.x] += t;
    __syncthreads();
  }
  int off = blocksum[blockIdx.x] + part[threadIdx.x] - me;
#pragma unroll
  for (int i = 0; i < 4; ++i) {
    int idx = base + i;
    if (idx < N_NODES) {
      rowptr[idx] = off;
      cursor[idx] = off;
      off += c[i];
    }
  }
}

// XCD-affine fill from the group's bucket only
__global__ void fill_kernel(const unsigned long long* __restrict__ bkt,
                            const int* __restrict__ bcur, int* __restrict__ cursor,
                            unsigned* __restrict__ col) {
  const int g = blockIdx.x & 7;
  const int sub = blockIdx.x >> 3;
  const int total = bcur[g * 16];
  const unsigned long long* b = bkt + (size_t)g * BUCKET_CAP;
  for (int i = sub * 256 + (int)threadIdx.x; i < total; i += FILL_SUB * 256) {
    unsigned long long ev = __builtin_nontemporal_load(b + i);
    unsigned d = (unsigned)ev;
    unsigned payload = (unsigned)(ev >> 32);
    int p = atomicAdd(&cursor[d], 1);
    col[p] = payload;
  }
}

// ---------------- fp32 -> bf16 cast ----------------

__global__ void cast_bf16(const float* __restrict__ in, ushort* __restrict__ out, int n4) {
  int i = blockIdx.x * blockDim.x + threadIdx.x;
  if (i >= n4) return;
  float4 v = reinterpret_cast<const float4*>(in)[i];
  ushort4 o = make_ushort4(f2bf(v.x), f2bf(v.y), f2bf(v.z), f2bf(v.w));
  reinterpret_cast<ushort4*>(out)[i] = o;
}

// ---------------- weight pre-transpose ----------------
// Wt1 [64][64] @0 | Wt2 [128][128] @4096 | Wt3r [128][64] @20480 | Wt3o [128][64] @28672

__global__ void wtrans_kernel(const float* __restrict__ W1rel, const float* __restrict__ W1root,
                              const float* __restrict__ W2rel, const float* __restrict__ W2root,
                              const float* __restrict__ W3rel, const float* __restrict__ W3root,
                              float* __restrict__ Wt) {
  int i = blockIdx.x * blockDim.x + threadIdx.x;
  if (i >= 36864) return;
  float v;
  if (i < 4096) {
    int k = i >> 6, j = i & 63;
    v = (k < 32) ? W1rel[j * 32 + k] : W1root[j * 32 + (k - 32)];
  } else if (i < 20480) {
    int r = i - 4096;
    int k = r >> 7, j = r & 127;
    v = (k < 64) ? W2rel[j * 64 + k] : W2root[j * 64 + (k - 64)];
  } else if (i < 28672) {
    int r = i - 20480;
    int k = r >> 6, j = r & 63;
    v = W3rel[j * 128 + k];
  } else {
    int r = i - 28672;
    int k = r >> 6, j = r & 63;
    v = W3root[j * 128 + k];
  }
  Wt[i] = v;
}

// ---------------- gather-side segment sums (bf16 rows in, bf16/fp32 out) ----------------

#define SRC_OF(v) ((v) & 0x1FFFFu)
#define W_OF(v) __uint_as_float(((v) >> 17) << 16)

__device__ __forceinline__ unsigned pack2bf(float a, float b) {
  return (unsigned)f2bf(a) | ((unsigned)f2bf(b) << 16);
}

__global__ void gather_d32_bf(const ushort* __restrict__ xb, const int* __restrict__ rowptr,
                              const unsigned* __restrict__ col, ushort* __restrict__ agg) {
  int gid = blockIdx.x * blockDim.x + threadIdx.x;
  int n = gid >> 2;
  if (n >= N_NODES) return;
  int c = gid & 3;
  int beg = rowptr[n], end = rowptr[n + 1];
  float acc[8];
#pragma unroll
  for (int i = 0; i < 8; ++i) acc[i] = 0.f;
  int p = beg;
  for (; p + 1 < end; p += 2) {
    unsigned e0 = col[p], e1 = col[p + 1];
    uint4 u0 = *reinterpret_cast<const uint4*>(xb + (size_t)SRC_OF(e0) * 32 + c * 8);
    uint4 u1 = *reinterpret_cast<const uint4*>(xb + (size_t)SRC_OF(e1) * 32 + c * 8);
    unsigned a0[4] = {u0.x, u0.y, u0.z, u0.w};
    unsigned a1[4] = {u1.x, u1.y, u1.z, u1.w};
#pragma unroll
    for (int i = 0; i < 4; ++i) {
      acc[2 * i]     += __uint_as_float(a0[i] << 16) + __uint_as_float(a1[i] << 16);
      acc[2 * i + 1] += __uint_as_float(a0[i] & 0xFFFF0000u) +
                        __uint_as_float(a1[i] & 0xFFFF0000u);
    }
  }
  if (p < end) {
    unsigned e0 = col[p];
    uint4 u0 = *reinterpret_cast<const uint4*>(xb + (size_t)SRC_OF(e0) * 32 + c * 8);
    unsigned a0[4] = {u0.x, u0.y, u0.z, u0.w};
#pragma unroll
    for (int i = 0; i < 4; ++i) {
      acc[2 * i]     += __uint_as_float(a0[i] << 16);
      acc[2 * i + 1] += __uint_as_float(a0[i] & 0xFFFF0000u);
    }
  }
  uint4 o = make_uint4(pack2bf(acc[0], acc[1]), pack2bf(acc[2], acc[3]),
                       pack2bf(acc[4], acc[5]), pack2bf(acc[6], acc[7]));
  *reinterpret_cast<uint4*>(agg + (size_t)n * 32 + c * 8) = o;
}

template <bool WEIGHTED, bool TRANS, bool OUTB16>
__global__ void gather_d64_bf(const ushort* __restrict__ hb, const int* __restrict__ rowptr,
                              const unsigned* __restrict__ col,
                              const float* __restrict__ sc, const float* __restrict__ sh,
                              void* __restrict__ aggv) {
  int gid = blockIdx.x * blockDim.x + threadIdx.x;
  int n = gid >> 3;
  if (n >= N_NODES) return;
  int c = gid & 7;
  int beg = rowptr[n], end = rowptr[n + 1];
  float sc8[8], sh8[8];
  if (TRANS) {
#pragma unroll
    for (int i = 0; i < 8; ++i) {
      sc8[i] = sc[c * 8 + i];
      sh8[i] = sh[c * 8 + i];
    }
  }
  float acc[8];
#pragma unroll
  for (int i = 0; i < 8; ++i) acc[i] = 0.f;

  auto body = [&](unsigned ev, const uint4& u) {
    float w = WEIGHTED ? W_OF(ev) : 1.f;
    unsigned uu[4] = {u.x, u.y, u.z, u.w};
#pragma unroll
    for (int i = 0; i < 4; ++i) {
      float lo = __uint_as_float(uu[i] << 16);
      float hi = __uint_as_float(uu[i] & 0xFFFF0000u);
      if (TRANS) {
        lo = fmaxf(fmaf(lo, sc8[2 * i], sh8[2 * i]), 0.f);
        hi = fmaxf(fmaf(hi, sc8[2 * i + 1], sh8[2 * i + 1]), 0.f);
      }
      if (WEIGHTED) {
        acc[2 * i]     = fmaf(lo, w, acc[2 * i]);
        acc[2 * i + 1] = fmaf(hi, w, acc[2 * i + 1]);
      } else {
        acc[2 * i]     += lo;
        acc[2 * i + 1] += hi;
      }
    }
  };

  int p = beg;
  for (; p + 1 < end; p += 2) {
    unsigned e0 = col[p], e1 = col[p + 1];
    uint4 u0 = *reinterpret_cast<const uint4*>(hb + (size_t)SRC_OF(e0) * 64 + c * 8);
    uint4 u1 = *reinterpret_cast<const uint4*>(hb + (size_t)SRC_OF(e1) * 64 + c * 8);
    body(e0, u0);
    body(e1, u1);
  }
  if (p < end) {
    unsigned e0 = col[p];
    uint4 u0 = *reinterpret_cast<const uint4*>(hb + (size_t)SRC_OF(e0) * 64 + c * 8);
    body(e0, u0);
  }
  if constexpr (OUTB16) {
    uint4 o = make_uint4(pack2bf(acc[0], acc[1]), pack2bf(acc[2], acc[3]),
                         pack2bf(acc[4], acc[5]), pack2bf(acc[6], acc[7]));
    *reinterpret_cast<uint4*>((ushort*)aggv + (size_t)n * 64 + c * 8) = o;
  } else {
    float* op = (float*)aggv + (size_t)n * 64 + c * 8;
    *reinterpret_cast<float4*>(op)     = make_float4(acc[0], acc[1], acc[2], acc[3]);
    *reinterpret_cast<float4*>(op + 4) = make_float4(acc[4], acc[5], acc[6], acc[7]);
  }
}

// ---------------- LDS-tiled node GEMM (BK=32, pre-transposed W) ----------------

template <int K1, int K2, int DO, int A1B16, int A2B16, int TA1, int TA2, int RADD,
          int STATS, int OUTM>
__global__ __launch_bounds__(256, 4) void gemm_node(
    const void* __restrict__ A1v, const void* __restrict__ A2v,
    const float* __restrict__ Wt,
    const float* __restrict__ sc, const float* __restrict__ sh,
    const float* __restrict__ R, float* __restrict__ out, ushort* __restrict__ outb,
    float* __restrict__ sums) {
  constexpr int K = K1 + K2;
  constexpr int NC = K / 32;
  constexpr int NJB = DO / 64;
  __shared__ __align__(16) float A_lds[64][36];
  __shared__ __align__(16) float W_lds[32][DO];

  const int tid = threadIdx.x;
  const int tx = tid & 15, ty = tid >> 4;
  const int nbase = blockIdx.x * 64;

  float4 acc[4][NJB];
#pragma unroll
  for (int i = 0; i < 4; ++i)
#pragma unroll
    for (int jb = 0; jb < NJB; ++jb) acc[i][jb] = make_float4(0.f, 0.f, 0.f, 0.f);

#pragma unroll 1
  for (int c = 0; c < NC; ++c) {
    const int kb = c * 32;
    if (c) __syncthreads();
#pragma unroll
    for (int it = 0; it < 2; ++it) {
      int idx = it * 256 + tid;
      int nl = idx >> 3;
      int kq = (idx & 7) * 4;
      int k = kb + kq;
      int ng = nbase + nl;
      float4 v = make_float4(0.f, 0.f, 0.f, 0.f);
      bool isA1 = (K2 == 0) || (k < K1);
      if (ng < N_NODES) {
        if (isA1) {
          if constexpr (A1B16) {
            uint2 u = *reinterpret_cast<const uint2*>(
                (const ushort*)A1v + (size_t)ng * K1 + k);
            v.x = __uint_as_float(u.x << 16);
            v.y = __uint_as_float(u.x & 0xFFFF0000u);
            v.z = __uint_as_float(u.y << 16);
            v.w = __uint_as_float(u.y & 0xFFFF0000u);
          } else {
            v = *reinterpret_cast<const float4*>((const float*)A1v + (size_t)ng * K1 + k);
          }
        } else {
          if constexpr (A2B16) {
            uint2 u = *reinterpret_cast<const uint2*>(
                (const ushort*)A2v + (size_t)ng * K2 + (k - K1));
            v.x = __uint_as_float(u.x << 16);
            v.y = __uint_as_float(u.x & 0xFFFF0000u);
            v.z = __uint_as_float(u.y << 16);
            v.w = __uint_as_float(u.y & 0xFFFF0000u);
          } else {
            v = *reinterpret_cast<const float4*>(
                (const float*)A2v + (size_t)ng * K2 + (k - K1));
          }
        }
      }
      if constexpr (TA1) {
        if (isA1) {
          float4 s4 = *reinterpret_cast<const float4*>(sc + k);
          float4 h4 = *reinterpret_cast<const float4*>(sh + k);
          v.x = fmaxf(fmaf(v.x, s4.x, h4.x), 0.f);
          v.y = fmaxf(fmaf(v.y, s4.y, h4.y), 0.f);
          v.z = fmaxf(fmaf(v.z, s4.z, h4.z), 0.f);
          v.w = fmaxf(fmaf(v.w, s4.w, h4.w), 0.f);
        }
      }
      if constexpr (TA2 && K2 > 0) {
        if (!isA1) {
          float4 s4 = *reinterpret_cast<const float4*>(sc + (k - K1));
          float4 h4 = *reinterpret_cast<const float4*>(sh + (k - K1));
          v.x = fmaxf(fmaf(v.x, s4.x, h4.x), 0.f);
          v.y = fmaxf(fmaf(v.y, s4.y, h4.y), 0.f);
          v.z = fmaxf(fmaf(v.z, s4.z, h4.z), 0.f);
          v.w = fmaxf(fmaf(v.w, s4.w, h4.w), 0.f);
        }
      }
      *reinterpret_cast<float4*>(&A_lds[nl][kq]) = v;
    }
    {
      const float4* wsrc = reinterpret_cast<const float4*>(Wt + (size_t)kb * DO);
      float4* wdst = reinterpret_cast<float4*>(&W_lds[0][0]);
#pragma unroll
      for (int it = 0; it < DO / 32; ++it)
        wdst[it * 256 + tid] = wsrc[it * 256 + tid];
    }
    __syncthreads();
#pragma unroll 2
    for (int k4 = 0; k4 < 8; ++k4) {
      float4 a[4];
#pragma unroll
      for (int i = 0; i < 4; ++i)
        a[i] = *reinterpret_cast<const float4*>(&A_lds[ty * 4 + i][k4 * 4]);
#pragma unroll
      for (int q = 0; q < 4; ++q) {
#pragma unroll
        for (int jb = 0; jb < NJB; ++jb) {
          float4 w = *reinterpret_cast<const float4*>(&W_lds[k4 * 4 + q][jb * 64 + tx * 4]);
#pragma unroll
          for (int i = 0; i < 4; ++i) {
            float av = reinterpret_cast<const float*>(&a[i])[q];
            acc[i][jb].x = fmaf(av, w.x, acc[i][jb].x);
            acc[i][jb].y = fmaf(av, w.y, acc[i][jb].y);
            acc[i][jb].z = fmaf(av, w.z, acc[i][jb].z);
            acc[i][jb].w = fmaf(av, w.w, acc[i][jb].w);
          }
        }
      }
    }
  }
#pragma unroll
  for (int i = 0; i < 4; ++i) {
    int ng = nbase + ty * 4 + i;
    if (ng >= N_NODES) continue;
#pragma unroll
    for (int jb = 0; jb < NJB; ++jb) {
      if constexpr (RADD) {
        float4 rr = *reinterpret_cast<const float4*>(R + (size_t)ng * DO + jb * 64 + tx * 4);
        acc[i][jb].x += rr.x; acc[i][jb].y += rr.y;
        acc[i][jb].z += rr.z; acc[i][jb].w += rr.w;
      }
      size_t off = (size_t)ng * DO + jb * 64 + tx * 4;
      if constexpr (OUTM == 1) {
        ushort4 o = make_ushort4(f2bf(acc[i][jb].x), f2bf(acc[i][jb].y),
                                 f2bf(acc[i][jb].z), f2bf(acc[i][jb].w));
        *reinterpret_cast<ushort4*>((ushort*)out + off) = o;
      } else {
        *reinterpret_cast<float4*>(out + off) = acc[i][jb];
        if constexpr (OUTM == 2) {
          ushort4 o = make_ushort4(f2bf(acc[i][jb].x), f2bf(acc[i][jb].y),
                                   f2bf(acc[i][jb].z), f2bf(acc[i][jb].w));
          *reinterpret_cast<ushort4*>(outb + off) = o;
        }
      }
    }
  }
  if constexpr (STATS) {
    __syncthreads();
    float* sums_l = &A_lds[0][0];
    float* sq_l = &W_lds[0][0];
#pragma unroll
    for (int jb = 0; jb < NJB; ++jb) {
      float4 s = make_float4(0.f, 0.f, 0.f, 0.f);
      float4 q = make_float4(0.f, 0.f, 0.f, 0.f);
#pragma unroll
      for (int i = 0; i < 4; ++i) {
        if (nbase + ty * 4 + i < N_NODES) {
          float4 v = acc[i][jb];
          s.x += v.x; s.y += v.y; s.z += v.z; s.w += v.w;
          q.x = fmaf(v.x, v.x, q.x); q.y = fmaf(v.y, v.y, q.y);
          q.z = fmaf(v.z, v.z, q.z); q.w = fmaf(v.w, v.w, q.w);
        }
      }
      *reinterpret_cast<float4*>(&sums_l[ty * DO + jb * 64 + tx * 4]) = s;
      *reinterpret_cast<float4*>(&sq_l[ty * DO + jb * 64 + tx * 4]) = q;
    }
    __syncthreads();
    if (tid < DO) {
      float s = 0.f, q = 0.f;
#pragma unroll
      for (int t = 0; t < 16; ++t) {
        s += sums_l[t * DO + tid];
        q += sq_l[t * DO + tid];
      }
      unsafeAtomicAdd(&sums[tid], s);
      unsafeAtomicAdd(&sums[DO + tid], q);
    }
  }
}

// ---------------- BN finalize ----------------

__global__ void bn_finalize(const float* __restrict__ sums, const float* __restrict__ g,
                            const float* __restrict__ be, float* __restrict__ sc,
                            float* __restrict__ sh, int D) {
  int j = threadIdx.x;
  if (j >= D) return;
  const float invN = 1.f / (float)N_NODES;
  float mean = sums[j] * invN;
  float var = sums[D + j] * invN - mean * mean;
  float r = rsqrtf(var + EPSV);
  float scale = g[j] * r;
  sc[j] = scale;
  sh[j] = be[j] - mean * scale;
}

// ---------------- fused residual + classifier ----------------

__global__ __launch_bounds__(256) void final_fused(
    const float* __restrict__ h3p, const float* __restrict__ h1p,
    const float* __restrict__ sc1, const float* __restrict__ sh1,
    const float* __restrict__ sc3, const float* __restrict__ sh3,
    const float* __restrict__ Wc1, const float* __restrict__ bc1,
    const float* __restrict__ Wc2, const float* __restrict__ bc2,
    float* __restrict__ out) {
  __shared__ __align__(16) float t_lds[64][68];
  __shared__ __align__(16) float w1_lds[64][36];
  __shared__ __align__(16) float c_lds[64][36];
  __shared__ __align__(16) float w2_lds[64];
  __shared__ __align__(16) float b1_lds[32];
  __shared__ float b2_lds[2];
  const int tid = threadIdx.x;
  const int nbase = blockIdx.x * 64;

#pragma unroll
  for (int it = 0; it < 4; ++it) {
    int idx = it * 256 + tid;
    int nl = idx >> 4;
    int k = (idx & 15) * 4;
    int ng = nbase + nl;
    float4 v = make_float4(0.f, 0.f, 0.f, 0.f);
    if (ng < N_NODES) {
      float4 p = *reinterpret_cast<const float4*>(h3p + (size_t)ng * 64 + k);
      float4 u = *reinterpret_cast<const float4*>(h1p + (size_t)ng * 64 + k);
      float4 sa = *reinterpret_cast<const float4*>(sc1 + k);
      float4 ha = *reinterpret_cast<const float4*>(sh1 + k);
      float4 sb = *reinterpret_cast<const float4*>(sc3 + k);
      float4 hb = *reinterpret_cast<const float4*>(sh3 + k);
      float h1x = fmaxf(fmaf(u.x, sa.x, ha.x), 0.f);
      float h1y = fmaxf(fmaf(u.y, sa.y, ha.y), 0.f);
      float h1z = fmaxf(fmaf(u.z, sa.z, ha.z), 0.f);
      float h1w = fmaxf(fmaf(u.w, sa.w, ha.w), 0.f);
      v.x = fmaxf(fmaf(p.x, sb.x, hb.x) + h1x, 0.f);
      v.y = fmaxf(fmaf(p.y, sb.y, hb.y) + h1y, 0.f);
      v.z = fmaxf(fmaf(p.z, sb.z, hb.z) + h1z, 0.f);
      v.w = fmaxf(fmaf(p.w, sb.w, hb.w) + h1w, 0.f);
    }
    *reinterpret_cast<float4*>(&t_lds[nl][k]) = v;
  }
#pragma unroll
  for (int it = 0; it < 8; ++it) {
    int idx = it * 256 + tid;
    int j = idx >> 6;
    int k = idx & 63;
    w1_lds[k][j] = Wc1[(size_t)j * 64 + k];
  }
  if (tid < 64) w2_lds[tid] = Wc2[tid];
  else if (tid < 96) b1_lds[tid - 64] = bc1[tid - 64];
  else if (tid < 98) b2_lds[tid - 96] = bc2[tid - 96];
  __syncthreads();

  {
    const int tx = tid & 7, ty = tid >> 3;
    float4 a0c = make_float4(0.f, 0.f, 0.f, 0.f);
    float4 a1c = make_float4(0.f, 0.f, 0.f, 0.f);
#pragma unroll 4
    for (int k4 = 0; k4 < 16; ++k4) {
      float4 a0 = *reinterpret_cast<const float4*>(&t_lds[ty * 2 + 0][k4 * 4]);
      float4 a1 = *reinterpret_cast<const float4*>(&t_lds[ty * 2 + 1][k4 * 4]);
#pragma unroll
      for (int q = 0; q < 4; ++q) {
        float4 w = *reinterpret_cast<const float4*>(&w1_lds[k4 * 4 + q][tx * 4]);
        float a0q = reinterpret_cast<const float*>(&a0)[q];
        float a1q = reinterpret_cast<const float*>(&a1)[q];
        a0c.x = fmaf(a0q, w.x, a0c.x); a0c.y = fmaf(a0q, w.y, a0c.y);
        a0c.z = fmaf(a0q, w.z, a0c.z); a0c.w = fmaf(a0q, w.w, a0c.w);
        a1c.x = fmaf(a1q, w.x, a1c.x); a1c.y = fmaf(a1q, w.y, a1c.y);
        a1c.z = fmaf(a1q, w.z, a1c.z); a1c.w = fmaf(a1q, w.w, a1c.w);
      }
    }
    float4 b = *reinterpret_cast<const float4*>(&b1_lds[tx * 4]);
    a0c.x = fmaxf(a0c.x + b.x, 0.f); a0c.y = fmaxf(a0c.y + b.y, 0.f);
    a0c.z = fmaxf(a0c.z + b.z, 0.f); a0c.w = fmaxf(a0c.w + b.w, 0.f);
    a1c.x = fmaxf(a1c.x + b.x, 0.f); a1c.y = fmaxf(a1c.y + b.y, 0.f);
    a1c.z = fmaxf(a1c.z + b.z, 0.f); a1c.w = fmaxf(a1c.w + b.w, 0.f);
    *reinterpret_cast<float4*>(&c_lds[ty * 2 + 0][tx * 4]) = a0c;
    *reinterpret_cast<float4*>(&c_lds[ty * 2 + 1][tx * 4]) = a1c;
  }
  __syncthreads();

  if (tid < 128) {
    int nl = tid >> 1, o = tid & 1;
    int ng = nbase + nl;
    if (ng < N_NODES) {
      float s = b2_lds[o];
#pragma unroll
      for (int k = 0; k < 32; ++k) s = fmaf(c_lds[nl][k], w2_lds[o * 32 + k], s);
      out[(size_t)ng * 2 + o] = s;
    }
  }
}

// ---------------- launcher ----------------

extern "C" void kernel_launch(void* const* d_in, const int* in_sizes, int n_in,
                              void* d_out, int out_size, void* d_ws, size_t ws_size,
                              hipStream_t stream) {
  const float* x      = (const float*)d_in[0];
  const int*   ei     = (const int*)d_in[1];
  const float* ew     = (const float*)d_in[2];
  const float* W1rel  = (const float*)d_in[3];
  const float* W1root = (const float*)d_in[5];
  const float* W2rel  = (const float*)d_in[6];
  const float* W2root = (const float*)d_in[8];
  const float* W3rel  = (const float*)d_in[9];
  const float* W3root = (const float*)d_in[11];
  const float* g1  = (const float*)d_in[12];
  const float* be1 = (const float*)d_in[13];
  const float* g2  = (const float*)d_in[14];
  const float* be2 = (const float*)d_in[15];
  const float* g3  = (const float*)d_in[16];
  const float* be3 = (const float*)d_in[17];
  const float* Wc1 = (const float*)d_in[18];
  const float* bc1 = (const float*)d_in[19];
  const float* Wc2 = (const float*)d_in[20];
  const float* bc2 = (const float*)d_in[21];

  float* ws = (float*)d_ws;
  const size_t NF = (size_t)N_NODES * 64;
  float* A = ws;            // agg1b(bf16) -> agg2b(bf16) -> agg3(fp32 N*64)
  float* B = ws + NF;       // xb(bf16) -> y2b(bf16) -> h3pre(fp32 N*64)
  float* C = ws + 2 * NF;   // h1pre fp32, live to the end
  float* E = ws + 3 * NF;   // h1preb(bf16) -> h2preb(bf16 N*128)
  float* X = ws + 5 * NF;
  float* S = X;                                 // 1024 floats
  int* rowptr   = (int*)(X + 1024);             // N+2
  int* cnt      = rowptr + (N_NODES + 2);       // N
  int* cursor   = cnt + N_NODES;                // N
  int* blocksum = cursor + N_NODES;             // 128
  int* bcur     = blocksum + 128;               // 128 (8 counters, 64B apart)
  unsigned* col = (unsigned*)(bcur + 130);      // E packed (w15|src17), 4B; +2 pads to 8B
  float* Wt     = (float*)(col + N_EDGES);      // 36864 floats
  unsigned long long* bkt = (unsigned long long*)(Wt + 36864);  // 8*BUCKET_CAP entries
  float* Wt1  = Wt;
  float* Wt2  = Wt + 4096;
  float* Wt3r = Wt + 20480;
  float* Wt3o = Wt + 28672;

  ushort* agg1b  = (ushort*)A;
  ushort* agg2b  = (ushort*)A;
  ushort* xb     = (ushort*)B;
  ushort* y2b    = (ushort*)B;
  ushort* h1preb = (ushort*)E;
  ushort* h2preb = (ushort*)E;

  hipMemsetAsync(S, 0, 1024 * sizeof(float), stream);
  hipMemsetAsync(cnt, 0, N_NODES * sizeof(int), stream);
  hipMemsetAsync(bcur, 0, 128 * sizeof(int), stream);

  const int tileBlocks = (N_NODES + 63) / 64;  // 1563

  // independent prep
  cast_bf16<<<(N_NODES * 32 / 4 + 255) / 256, 256, 0, stream>>>(x, xb, N_NODES * 32 / 4);
  wtrans_kernel<<<144, 256, 0, stream>>>(W1rel, W1root, W2rel, W2root, W3rel, W3root, Wt);

  // edge bucketize (1 pass), then XCD-affine CSR build from buckets
  bucket_kernel<<<1024, 256, 0, stream>>>(ei, ew, bcur, bkt);
  hist_kernel<<<8 * FILL_SUB, 256, 0, stream>>>(bkt, bcur, cnt);
  scan_phase1<<<SCAN_NB, 256, 0, stream>>>(cnt, blocksum);
  scan_phase2<<<1, 128, 0, stream>>>(blocksum, rowptr);
  scan_phase3<<<SCAN_NB, 256, 0, stream>>>(cnt, blocksum, rowptr, cursor);
  fill_kernel<<<8 * FILL_SUB, 256, 0, stream>>>(bkt, bcur, cursor, col);

  // ---- layer 1 ----
  gather_d32_bf<<<(N_NODES * 4 + 255) / 256, 256, 0, stream>>>(xb, rowptr, col, agg1b);
  gemm_node<32, 32, 64, 1, 1, 0, 0, 0, 1, 2><<<tileBlocks, 256, 0, stream>>>(
      agg1b, xb, Wt1, nullptr, nullptr, nullptr, C, h1preb, S);
  bn_finalize<<<1, 128, 0, stream>>>(S, g1, be1, S + 128, S + 192, 64);

  // ---- layer 2 ----
  gather_d64_bf<false, true, true><<<(N_NODES * 8 + 255) / 256, 256, 0, stream>>>(
      h1preb, rowptr, col, S + 128, S + 192, agg2b);
  gemm_node<64, 64, 128, 1, 0, 0, 1, 0, 1, 1><<<tileBlocks, 256, 0, stream>>>(
      agg2b, C, Wt2, S + 128, S + 192, nullptr, (float*)h2preb, nullptr, S + 256);
  bn_finalize<<<1, 128, 0, stream>>>(S + 256, g2, be2, S + 512, S + 640, 128);

  // y2b = bf16( relu(bn2(h2preb)) @ W3rel^T )
  gemm_node<128, 0, 64, 1, 0, 1, 0, 0, 0, 1><<<tileBlocks, 256, 0, stream>>>(
      h2preb, nullptr, Wt3r, S + 512, S + 640, nullptr, (float*)y2b, nullptr, nullptr);

  // ---- layer 3 ----
  gather_d64_bf<true, false, false><<<(N_NODES * 8 + 255) / 256, 256, 0, stream>>>(
      y2b, rowptr, col, nullptr, nullptr, A);
  gemm_node<128, 0, 64, 1, 0, 1, 0, 1, 1, 0><<<tileBlocks, 256, 0, stream>>>(
      h2preb, nullptr, Wt3o, S + 512, S + 640, A, B, nullptr, S + 768);
  bn_finalize<<<1, 128, 0, stream>>>(S + 768, g3, be3, S + 896, S + 960, 64);

  // ---- residual + classifier ----
  final_fused<<<tileBlocks, 256, 0, stream>>>(B, C, S + 128, S + 192, S + 896, S + 960,
                                              Wc1, bc1, Wc2, bc2, (float*)d_out);
}

// Round 15
// 471.643 us; speedup vs baseline: 1.0588x; 1.0588x over previous
//
#include <hip/hip_runtime.h>

#define N_NODES 100000
#define N_EDGES 1600000
#define EPSV 1e-5f

__device__ __forceinline__ ushort f2bf(float f) {
  unsigned u = __float_as_uint(f);
  unsigned r = (u + 0x7FFFu + ((u >> 16) & 1u)) >> 16;
  return (ushort)r;
}

// ---------------- CSR-by-destination build (XCD-affine, 8 groups) ----------------

#define FILL_SUB 256
#define GRP_W 12500

__global__ void hist_kernel(const int* __restrict__ ei, int* __restrict__ cnt) {
  const int g = blockIdx.x & 7;
  const int sub = blockIdx.x >> 3;
  const int lo = g * GRP_W, hi = lo + GRP_W;
  const int EPB = (N_EDGES + FILL_SUB - 1) / FILL_SUB;
  const int beg = sub * EPB;
  const int end = min(beg + EPB, N_EDGES);
  for (int e = beg + (int)threadIdx.x; e < end; e += (int)blockDim.x) {
    int d = __builtin_nontemporal_load(ei + N_EDGES + e);
    if (d >= lo && d < hi) atomicAdd(&cnt[d], 1);
  }
}

#define SCAN_BLK 1024
#define SCAN_NB ((N_NODES + SCAN_BLK - 1) / SCAN_BLK)  // 98

__global__ void scan_phase1(const int* __restrict__ cnt, int* __restrict__ blocksum) {
  __shared__ int part[256];
  int base = blockIdx.x * SCAN_BLK + threadIdx.x * 4;
  int s = 0;
#pragma unroll
  for (int i = 0; i < 4; ++i) {
    int idx = base + i;
    if (idx < N_NODES) s += cnt[idx];
  }
  part[threadIdx.x] = s;
  __syncthreads();
  for (int d = 128; d > 0; d >>= 1) {
    if (threadIdx.x < d) part[threadIdx.x] += part[threadIdx.x + d];
    __syncthreads();
  }
  if (threadIdx.x == 0) blocksum[blockIdx.x] = part[0];
}

__global__ void scan_phase2(int* __restrict__ blocksum, int* __restrict__ rowptr) {
  __shared__ int part[128];
  int tid = threadIdx.x;
  int v = (tid < SCAN_NB) ? blocksum[tid] : 0;
  part[tid] = v;
  __syncthreads();
  for (int d = 1; d < 128; d <<= 1) {
    int t = (tid >= d) ? part[tid - d] : 0;
    __syncthreads();
    part[tid] += t;
    __syncthreads();
  }
  if (tid < SCAN_NB) blocksum[tid] = part[tid] - v;  // exclusive
  if (tid == 127) rowptr[N_NODES] = part[127];
}

__global__ void scan_phase3(const int* __restrict__ cnt, const int* __restrict__ blocksum,
                            int* __restrict__ rowptr, int* __restrict__ cursor) {
  __shared__ int part[256];
  int base = blockIdx.x * SCAN_BLK + threadIdx.x * 4;
  int c[4];
  int s = 0;
#pragma unroll
  for (int i = 0; i < 4; ++i) {
    int idx = base + i;
    c[i] = (idx < N_NODES) ? cnt[idx] : 0;
    s += c[i];
  }
  part[threadIdx.x] = s;
  __syncthreads();
  int me = s;
  for (int d = 1; d < 256; d <<= 1) {
    int t = (threadIdx.x >= d) ? part[threadIdx.x - d] : 0;
    __syncthreads();
    part[threadIdx.x] += t;
    __syncthreads();
  }
  int off = blocksum[blockIdx.x] + part[threadIdx.x] - me;
#pragma unroll
  for (int i = 0; i < 4; ++i) {
    int idx = base + i;
    if (idx < N_NODES) {
      rowptr[idx] = off;
      cursor[idx] = off;
      off += c[i];
    }
  }
}

__global__ void fill_kernel(const int* __restrict__ ei, const float* __restrict__ ew,
                            int* __restrict__ cursor, unsigned* __restrict__ col) {
  const int g = blockIdx.x & 7;
  const int sub = blockIdx.x >> 3;
  const int lo = g * GRP_W, hi = lo + GRP_W;
  const int EPB = (N_EDGES + FILL_SUB - 1) / FILL_SUB;
  const int beg = sub * EPB;
  const int end = min(beg + EPB, N_EDGES);
  for (int e = beg + (int)threadIdx.x; e < end; e += (int)blockDim.x) {
    int d = __builtin_nontemporal_load(ei + N_EDGES + e);
    if (d < lo || d >= hi) continue;
    int p = atomicAdd(&cursor[d], 1);
    int src = __builtin_nontemporal_load(ei + e);
    float w = __builtin_nontemporal_load(ew + e);
    col[p] = ((unsigned)f2bf(w) << 17) | (unsigned)src;
  }
}

// ---------------- fp32 -> bf16 cast ----------------

__global__ void cast_bf16(const float* __restrict__ in, ushort* __restrict__ out, int n4) {
  int i = blockIdx.x * blockDim.x + threadIdx.x;
  if (i >= n4) return;
  float4 v = reinterpret_cast<const float4*>(in)[i];
  ushort4 o = make_ushort4(f2bf(v.x), f2bf(v.y), f2bf(v.z), f2bf(v.w));
  reinterpret_cast<ushort4*>(out)[i] = o;
}

// ---------------- weight pre-transpose ----------------
// Wt1 [64][64] @0 | Wt2 [128][128] @4096 | Wt3r [128][64] @20480 | Wt3o [128][64] @28672

__global__ void wtrans_kernel(const float* __restrict__ W1rel, const float* __restrict__ W1root,
                              const float* __restrict__ W2rel, const float* __restrict__ W2root,
                              const float* __restrict__ W3rel, const float* __restrict__ W3root,
                              float* __restrict__ Wt) {
  int i = blockIdx.x * blockDim.x + threadIdx.x;
  if (i >= 36864) return;
  float v;
  if (i < 4096) {
    int k = i >> 6, j = i & 63;
    v = (k < 32) ? W1rel[j * 32 + k] : W1root[j * 32 + (k - 32)];
  } else if (i < 20480) {
    int r = i - 4096;
    int k = r >> 7, j = r & 127;
    v = (k < 64) ? W2rel[j * 64 + k] : W2root[j * 64 + (k - 64)];
  } else if (i < 28672) {
    int r = i - 20480;
    int k = r >> 6, j = r & 63;
    v = W3rel[j * 128 + k];
  } else {
    int r = i - 28672;
    int k = r >> 6, j = r & 63;
    v = W3root[j * 128 + k];
  }
  Wt[i] = v;
}

// ---------------- gather-side segment sums (bf16 rows in, 16B loads, 4x unroll) --------

#define SRC_OF(v) ((v) & 0x1FFFFu)
#define W_OF(v) __uint_as_float(((v) >> 17) << 16)

__device__ __forceinline__ unsigned pack2bf(float a, float b) {
  return (unsigned)f2bf(a) | ((unsigned)f2bf(b) << 16);
}

__global__ void gather_d32_bf(const ushort* __restrict__ xb, const int* __restrict__ rowptr,
                              const unsigned* __restrict__ col, ushort* __restrict__ agg) {
  int gid = blockIdx.x * blockDim.x + threadIdx.x;
  int n = gid >> 2;
  if (n >= N_NODES) return;
  int c = gid & 3;
  int beg = rowptr[n], end = rowptr[n + 1];
  float acc[8];
#pragma unroll
  for (int i = 0; i < 8; ++i) acc[i] = 0.f;

  auto body = [&](const uint4& u) {
    unsigned uu[4] = {u.x, u.y, u.z, u.w};
#pragma unroll
    for (int i = 0; i < 4; ++i) {
      acc[2 * i]     += __uint_as_float(uu[i] << 16);
      acc[2 * i + 1] += __uint_as_float(uu[i] & 0xFFFF0000u);
    }
  };

  int p = beg;
  for (; p + 3 < end; p += 4) {
    unsigned e0 = col[p], e1 = col[p + 1], e2 = col[p + 2], e3 = col[p + 3];
    uint4 u0 = *reinterpret_cast<const uint4*>(xb + (size_t)SRC_OF(e0) * 32 + c * 8);
    uint4 u1 = *reinterpret_cast<const uint4*>(xb + (size_t)SRC_OF(e1) * 32 + c * 8);
    uint4 u2 = *reinterpret_cast<const uint4*>(xb + (size_t)SRC_OF(e2) * 32 + c * 8);
    uint4 u3 = *reinterpret_cast<const uint4*>(xb + (size_t)SRC_OF(e3) * 32 + c * 8);
    body(u0); body(u1); body(u2); body(u3);
  }
  for (; p < end; ++p) {
    unsigned e0 = col[p];
    uint4 u0 = *reinterpret_cast<const uint4*>(xb + (size_t)SRC_OF(e0) * 32 + c * 8);
    body(u0);
  }
  uint4 o = make_uint4(pack2bf(acc[0], acc[1]), pack2bf(acc[2], acc[3]),
                       pack2bf(acc[4], acc[5]), pack2bf(acc[6], acc[7]));
  *reinterpret_cast<uint4*>(agg + (size_t)n * 32 + c * 8) = o;
}

template <bool WEIGHTED, bool TRANS, bool OUTB16>
__global__ void gather_d64_bf(const ushort* __restrict__ hb, const int* __restrict__ rowptr,
                              const unsigned* __restrict__ col,
                              const float* __restrict__ sc, const float* __restrict__ sh,
                              void* __restrict__ aggv) {
  int gid = blockIdx.x * blockDim.x + threadIdx.x;
  int n = gid >> 3;
  if (n >= N_NODES) return;
  int c = gid & 7;
  int beg = rowptr[n], end = rowptr[n + 1];
  float sc8[8], sh8[8];
  if (TRANS) {
#pragma unroll
    for (int i = 0; i < 8; ++i) {
      sc8[i] = sc[c * 8 + i];
      sh8[i] = sh[c * 8 + i];
    }
  }
  float acc[8];
#pragma unroll
  for (int i = 0; i < 8; ++i) acc[i] = 0.f;

  auto body = [&](unsigned ev, const uint4& u) {
    float w = WEIGHTED ? W_OF(ev) : 1.f;
    unsigned uu[4] = {u.x, u.y, u.z, u.w};
#pragma unroll
    for (int i = 0; i < 4; ++i) {
      float lo = __uint_as_float(uu[i] << 16);
      float hi = __uint_as_float(uu[i] & 0xFFFF0000u);
      if (TRANS) {
        lo = fmaxf(fmaf(lo, sc8[2 * i], sh8[2 * i]), 0.f);
        hi = fmaxf(fmaf(hi, sc8[2 * i + 1], sh8[2 * i + 1]), 0.f);
      }
      if (WEIGHTED) {
        acc[2 * i]     = fmaf(lo, w, acc[2 * i]);
        acc[2 * i + 1] = fmaf(hi, w, acc[2 * i + 1]);
      } else {
        acc[2 * i]     += lo;
        acc[2 * i + 1] += hi;
      }
    }
  };

  int p = beg;
  for (; p + 3 < end; p += 4) {
    unsigned e0 = col[p], e1 = col[p + 1], e2 = col[p + 2], e3 = col[p + 3];
    uint4 u0 = *reinterpret_cast<const uint4*>(hb + (size_t)SRC_OF(e0) * 64 + c * 8);
    uint4 u1 = *reinterpret_cast<const uint4*>(hb + (size_t)SRC_OF(e1) * 64 + c * 8);
    uint4 u2 = *reinterpret_cast<const uint4*>(hb + (size_t)SRC_OF(e2) * 64 + c * 8);
    uint4 u3 = *reinterpret_cast<const uint4*>(hb + (size_t)SRC_OF(e3) * 64 + c * 8);
    body(e0, u0); body(e1, u1); body(e2, u2); body(e3, u3);
  }
  for (; p < end; ++p) {
    unsigned e0 = col[p];
    uint4 u0 = *reinterpret_cast<const uint4*>(hb + (size_t)SRC_OF(e0) * 64 + c * 8);
    body(e0, u0);
  }
  if constexpr (OUTB16) {
    uint4 o = make_uint4(pack2bf(acc[0], acc[1]), pack2bf(acc[2], acc[3]),
                         pack2bf(acc[4], acc[5]), pack2bf(acc[6], acc[7]));
    *reinterpret_cast<uint4*>((ushort*)aggv + (size_t)n * 64 + c * 8) = o;
  } else {
    float* op = (float*)aggv + (size_t)n * 64 + c * 8;
    *reinterpret_cast<float4*>(op)     = make_float4(acc[0], acc[1], acc[2], acc[3]);
    *reinterpret_cast<float4*>(op + 4) = make_float4(acc[4], acc[5], acc[6], acc[7]);
  }
}

// ---------------- LDS-tiled node GEMM (BK=32, pre-transposed W) ----------------

template <int K1, int K2, int DO, int A1B16, int A2B16, int TA1, int TA2, int RADD,
          int STATS, int OUTM>
__global__ __launch_bounds__(256, 4) void gemm_node(
    const void* __restrict__ A1v, const void* __restrict__ A2v,
    const float* __restrict__ Wt,
    const float* __restrict__ sc, const float* __restrict__ sh,
    const float* __restrict__ R, float* __restrict__ out, ushort* __restrict__ outb,
    float* __restrict__ sums) {
  constexpr int K = K1 + K2;
  constexpr int NC = K / 32;
  constexpr int NJB = DO / 64;
  __shared__ __align__(16) float A_lds[64][36];
  __shared__ __align__(16) float W_lds[32][DO];

  const int tid = threadIdx.x;
  const int tx = tid & 15, ty = tid >> 4;
  const int nbase = blockIdx.x * 64;

  float4 acc[4][NJB];
#pragma unroll
  for (int i = 0; i < 4; ++i)
#pragma unroll
    for (int jb = 0; jb < NJB; ++jb) acc[i][jb] = make_float4(0.f, 0.f, 0.f, 0.f);

#pragma unroll 1
  for (int c = 0; c < NC; ++c) {
    const int kb = c * 32;
    if (c) __syncthreads();
#pragma unroll
    for (int it = 0; it < 2; ++it) {
      int idx = it * 256 + tid;
      int nl = idx >> 3;
      int kq = (idx & 7) * 4;
      int k = kb + kq;
      int ng = nbase + nl;
      float4 v = make_float4(0.f, 0.f, 0.f, 0.f);
      bool isA1 = (K2 == 0) || (k < K1);
      if (ng < N_NODES) {
        if (isA1) {
          if constexpr (A1B16) {
            uint2 u = *reinterpret_cast<const uint2*>(
                (const ushort*)A1v + (size_t)ng * K1 + k);
            v.x = __uint_as_float(u.x << 16);
            v.y = __uint_as_float(u.x & 0xFFFF0000u);
            v.z = __uint_as_float(u.y << 16);
            v.w = __uint_as_float(u.y & 0xFFFF0000u);
          } else {
            v = *reinterpret_cast<const float4*>((const float*)A1v + (size_t)ng * K1 + k);
          }
        } else {
          if constexpr (A2B16) {
            uint2 u = *reinterpret_cast<const uint2*>(
                (const ushort*)A2v + (size_t)ng * K2 + (k - K1));
            v.x = __uint_as_float(u.x << 16);
            v.y = __uint_as_float(u.x & 0xFFFF0000u);
            v.z = __uint_as_float(u.y << 16);
            v.w = __uint_as_float(u.y & 0xFFFF0000u);
          } else {
            v = *reinterpret_cast<const float4*>(
                (const float*)A2v + (size_t)ng * K2 + (k - K1));
          }
        }
      }
      if constexpr (TA1) {
        if (isA1) {
          float4 s4 = *reinterpret_cast<const float4*>(sc + k);
          float4 h4 = *reinterpret_cast<const float4*>(sh + k);
          v.x = fmaxf(fmaf(v.x, s4.x, h4.x), 0.f);
          v.y = fmaxf(fmaf(v.y, s4.y, h4.y), 0.f);
          v.z = fmaxf(fmaf(v.z, s4.z, h4.z), 0.f);
          v.w = fmaxf(fmaf(v.w, s4.w, h4.w), 0.f);
        }
      }
      if constexpr (TA2 && K2 > 0) {
        if (!isA1) {
          float4 s4 = *reinterpret_cast<const float4*>(sc + (k - K1));
          float4 h4 = *reinterpret_cast<const float4*>(sh + (k - K1));
          v.x = fmaxf(fmaf(v.x, s4.x, h4.x), 0.f);
          v.y = fmaxf(fmaf(v.y, s4.y, h4.y), 0.f);
          v.z = fmaxf(fmaf(v.z, s4.z, h4.z), 0.f);
          v.w = fmaxf(fmaf(v.w, s4.w, h4.w), 0.f);
        }
      }
      *reinterpret_cast<float4*>(&A_lds[nl][kq]) = v;
    }
    {
      const float4* wsrc = reinterpret_cast<const float4*>(Wt + (size_t)kb * DO);
      float4* wdst = reinterpret_cast<float4*>(&W_lds[0][0]);
#pragma unroll
      for (int it = 0; it < DO / 32; ++it)
        wdst[it * 256 + tid] = wsrc[it * 256 + tid];
    }
    __syncthreads();
#pragma unroll 2
    for (int k4 = 0; k4 < 8; ++k4) {
      float4 a[4];
#pragma unroll
      for (int i = 0; i < 4; ++i)
        a[i] = *reinterpret_cast<const float4*>(&A_lds[ty * 4 + i][k4 * 4]);
#pragma unroll
      for (int q = 0; q < 4; ++q) {
#pragma unroll
        for (int jb = 0; jb < NJB; ++jb) {
          float4 w = *reinterpret_cast<const float4*>(&W_lds[k4 * 4 + q][jb * 64 + tx * 4]);
#pragma unroll
          for (int i = 0; i < 4; ++i) {
            float av = reinterpret_cast<const float*>(&a[i])[q];
            acc[i][jb].x = fmaf(av, w.x, acc[i][jb].x);
            acc[i][jb].y = fmaf(av, w.y, acc[i][jb].y);
            acc[i][jb].z = fmaf(av, w.z, acc[i][jb].z);
            acc[i][jb].w = fmaf(av, w.w, acc[i][jb].w);
          }
        }
      }
    }
  }
#pragma unroll
  for (int i = 0; i < 4; ++i) {
    int ng = nbase + ty * 4 + i;
    if (ng >= N_NODES) continue;
#pragma unroll
    for (int jb = 0; jb < NJB; ++jb) {
      if constexpr (RADD) {
        float4 rr = *reinterpret_cast<const float4*>(R + (size_t)ng * DO + jb * 64 + tx * 4);
        acc[i][jb].x += rr.x; acc[i][jb].y += rr.y;
        acc[i][jb].z += rr.z; acc[i][jb].w += rr.w;
      }
      size_t off = (size_t)ng * DO + jb * 64 + tx * 4;
      if constexpr (OUTM == 1) {
        ushort4 o = make_ushort4(f2bf(acc[i][jb].x), f2bf(acc[i][jb].y),
                                 f2bf(acc[i][jb].z), f2bf(acc[i][jb].w));
        *reinterpret_cast<ushort4*>((ushort*)out + off) = o;
      } else {
        *reinterpret_cast<float4*>(out + off) = acc[i][jb];
        if constexpr (OUTM == 2) {
          ushort4 o = make_ushort4(f2bf(acc[i][jb].x), f2bf(acc[i][jb].y),
                                   f2bf(acc[i][jb].z), f2bf(acc[i][jb].w));
          *reinterpret_cast<ushort4*>(outb + off) = o;
        }
      }
    }
  }
  if constexpr (STATS) {
    __syncthreads();
    float* sums_l = &A_lds[0][0];
    float* sq_l = &W_lds[0][0];
#pragma unroll
    for (int jb = 0; jb < NJB; ++jb) {
      float4 s = make_float4(0.f, 0.f, 0.f, 0.f);
      float4 q = make_float4(0.f, 0.f, 0.f, 0.f);
#pragma unroll
      for (int i = 0; i < 4; ++i) {
        if (nbase + ty * 4 + i < N_NODES) {
          float4 v = acc[i][jb];
          s.x += v.x; s.y += v.y; s.z += v.z; s.w += v.w;
          q.x = fmaf(v.x, v.x, q.x); q.y = fmaf(v.y, v.y, q.y);
          q.z = fmaf(v.z, v.z, q.z); q.w = fmaf(v.w, v.w, q.w);
        }
      }
      *reinterpret_cast<float4*>(&sums_l[ty * DO + jb * 64 + tx * 4]) = s;
      *reinterpret_cast<float4*>(&sq_l[ty * DO + jb * 64 + tx * 4]) = q;
    }
    __syncthreads();
    if (tid < DO) {
      float s = 0.f, q = 0.f;
#pragma unroll
      for (int t = 0; t < 16; ++t) {
        s += sums_l[t * DO + tid];
        q += sq_l[t * DO + tid];
      }
      unsafeAtomicAdd(&sums[tid], s);
      unsafeAtomicAdd(&sums[DO + tid], q);
    }
  }
}

// ---------------- BN finalize ----------------

__global__ void bn_finalize(const float* __restrict__ sums, const float* __restrict__ g,
                            const float* __restrict__ be, float* __restrict__ sc,
                            float* __restrict__ sh, int D) {
  int j = threadIdx.x;
  if (j >= D) return;
  const float invN = 1.f / (float)N_NODES;
  float mean = sums[j] * invN;
  float var = sums[D + j] * invN - mean * mean;
  float r = rsqrtf(var + EPSV);
  float scale = g[j] * r;
  sc[j] = scale;
  sh[j] = be[j] - mean * scale;
}

// ---------------- fused residual + classifier (h1pre in bf16) ----------------

__global__ __launch_bounds__(256) void final_fused(
    const float* __restrict__ h3p, const ushort* __restrict__ h1p,
    const float* __restrict__ sc1, const float* __restrict__ sh1,
    const float* __restrict__ sc3, const float* __restrict__ sh3,
    const float* __restrict__ Wc1, const float* __restrict__ bc1,
    const float* __restrict__ Wc2, const float* __restrict__ bc2,
    float* __restrict__ out) {
  __shared__ __align__(16) float t_lds[64][68];
  __shared__ __align__(16) float w1_lds[64][36];
  __shared__ __align__(16) float c_lds[64][36];
  __shared__ __align__(16) float w2_lds[64];
  __shared__ __align__(16) float b1_lds[32];
  __shared__ float b2_lds[2];
  const int tid = threadIdx.x;
  const int nbase = blockIdx.x * 64;

#pragma unroll
  for (int it = 0; it < 4; ++it) {
    int idx = it * 256 + tid;
    int nl = idx >> 4;
    int k = (idx & 15) * 4;
    int ng = nbase + nl;
    float4 v = make_float4(0.f, 0.f, 0.f, 0.f);
    if (ng < N_NODES) {
      float4 p = *reinterpret_cast<const float4*>(h3p + (size_t)ng * 64 + k);
      uint2 uu = *reinterpret_cast<const uint2*>(h1p + (size_t)ng * 64 + k);
      float ux = __uint_as_float(uu.x << 16);
      float uy = __uint_as_float(uu.x & 0xFFFF0000u);
      float uz = __uint_as_float(uu.y << 16);
      float uw = __uint_as_float(uu.y & 0xFFFF0000u);
      float4 sa = *reinterpret_cast<const float4*>(sc1 + k);
      float4 ha = *reinterpret_cast<const float4*>(sh1 + k);
      float4 sb = *reinterpret_cast<const float4*>(sc3 + k);
      float4 hb = *reinterpret_cast<const float4*>(sh3 + k);
      float h1x = fmaxf(fmaf(ux, sa.x, ha.x), 0.f);
      float h1y = fmaxf(fmaf(uy, sa.y, ha.y), 0.f);
      float h1z = fmaxf(fmaf(uz, sa.z, ha.z), 0.f);
      float h1w = fmaxf(fmaf(uw, sa.w, ha.w), 0.f);
      v.x = fmaxf(fmaf(p.x, sb.x, hb.x) + h1x, 0.f);
      v.y = fmaxf(fmaf(p.y, sb.y, hb.y) + h1y, 0.f);
      v.z = fmaxf(fmaf(p.z, sb.z, hb.z) + h1z, 0.f);
      v.w = fmaxf(fmaf(p.w, sb.w, hb.w) + h1w, 0.f);
    }
    *reinterpret_cast<float4*>(&t_lds[nl][k]) = v;
  }
#pragma unroll
  for (int it = 0; it < 8; ++it) {
    int idx = it * 256 + tid;
    int j = idx >> 6;
    int k = idx & 63;
    w1_lds[k][j] = Wc1[(size_t)j * 64 + k];
  }
  if (tid < 64) w2_lds[tid] = Wc2[tid];
  else if (tid < 96) b1_lds[tid - 64] = bc1[tid - 64];
  else if (tid < 98) b2_lds[tid - 96] = bc2[tid - 96];
  __syncthreads();

  {
    const int tx = tid & 7, ty = tid >> 3;
    float4 a0c = make_float4(0.f, 0.f, 0.f, 0.f);
    float4 a1c = make_float4(0.f, 0.f, 0.f, 0.f);
#pragma unroll 4
    for (int k4 = 0; k4 < 16; ++k4) {
      float4 a0 = *reinterpret_cast<const float4*>(&t_lds[ty * 2 + 0][k4 * 4]);
      float4 a1 = *reinterpret_cast<const float4*>(&t_lds[ty * 2 + 1][k4 * 4]);
#pragma unroll
      for (int q = 0; q < 4; ++q) {
        float4 w = *reinterpret_cast<const float4*>(&w1_lds[k4 * 4 + q][tx * 4]);
        float a0q = reinterpret_cast<const float*>(&a0)[q];
        float a1q = reinterpret_cast<const float*>(&a1)[q];
        a0c.x = fmaf(a0q, w.x, a0c.x); a0c.y = fmaf(a0q, w.y, a0c.y);
        a0c.z = fmaf(a0q, w.z, a0c.z); a0c.w = fmaf(a0q, w.w, a0c.w);
        a1c.x = fmaf(a1q, w.x, a1c.x); a1c.y = fmaf(a1q, w.y, a1c.y);
        a1c.z = fmaf(a1q, w.z, a1c.z); a1c.w = fmaf(a1q, w.w, a1c.w);
      }
    }
    float4 b = *reinterpret_cast<const float4*>(&b1_lds[tx * 4]);
    a0c.x = fmaxf(a0c.x + b.x, 0.f); a0c.y = fmaxf(a0c.y + b.y, 0.f);
    a0c.z = fmaxf(a0c.z + b.z, 0.f); a0c.w = fmaxf(a0c.w + b.w, 0.f);
    a1c.x = fmaxf(a1c.x + b.x, 0.f); a1c.y = fmaxf(a1c.y + b.y, 0.f);
    a1c.z = fmaxf(a1c.z + b.z, 0.f); a1c.w = fmaxf(a1c.w + b.w, 0.f);
    *reinterpret_cast<float4*>(&c_lds[ty * 2 + 0][tx * 4]) = a0c;
    *reinterpret_cast<float4*>(&c_lds[ty * 2 + 1][tx * 4]) = a1c;
  }
  __syncthreads();

  if (tid < 128) {
    int nl = tid >> 1, o = tid & 1;
    int ng = nbase + nl;
    if (ng < N_NODES) {
      float s = b2_lds[o];
#pragma unroll
      for (int k = 0; k < 32; ++k) s = fmaf(c_lds[nl][k], w2_lds[o * 32 + k], s);
      out[(size_t)ng * 2 + o] = s;
    }
  }
}

// ---------------- launcher ----------------

extern "C" void kernel_launch(void* const* d_in, const int* in_sizes, int n_in,
                              void* d_out, int out_size, void* d_ws, size_t ws_size,
                              hipStream_t stream) {
  const float* x      = (const float*)d_in[0];
  const int*   ei     = (const int*)d_in[1];
  const float* ew     = (const float*)d_in[2];
  const float* W1rel  = (const float*)d_in[3];
  const float* W1root = (const float*)d_in[5];
  const float* W2rel  = (const float*)d_in[6];
  const float* W2root = (const float*)d_in[8];
  const float* W3rel  = (const float*)d_in[9];
  const float* W3root = (const float*)d_in[11];
  const float* g1  = (const float*)d_in[12];
  const float* be1 = (const float*)d_in[13];
  const float* g2  = (const float*)d_in[14];
  const float* be2 = (const float*)d_in[15];
  const float* g3  = (const float*)d_in[16];
  const float* be3 = (const float*)d_in[17];
  const float* Wc1 = (const float*)d_in[18];
  const float* bc1 = (const float*)d_in[19];
  const float* Wc2 = (const float*)d_in[20];
  const float* bc2 = (const float*)d_in[21];

  float* ws = (float*)d_ws;
  const size_t NF = (size_t)N_NODES * 64;
  float* A = ws;            // agg1b(bf16) -> agg2b(bf16) -> agg3(fp32 N*64)
  float* B = ws + NF;       // xb(bf16) -> y2b(bf16) -> h3pre(fp32 N*64)
  float* C = ws + 2 * NF;   // h1preb (bf16 N*64), live to the end
  float* E = ws + 3 * NF;   // h2preb (bf16 N*128)
  float* X = ws + 5 * NF;
  float* S = X;                                 // 1024 floats
  int* rowptr   = (int*)(X + 1024);             // N+2
  int* cnt      = rowptr + (N_NODES + 2);       // N
  int* cursor   = cnt + N_NODES;                // N
  int* blocksum = cursor + N_NODES;             // 128
  unsigned* col = (unsigned*)(blocksum + 128);  // E packed (w15|src17), 4B
  float* Wt     = (float*)(col + N_EDGES);      // 36864 floats
  float* Wt1  = Wt;
  float* Wt2  = Wt + 4096;
  float* Wt3r = Wt + 20480;
  float* Wt3o = Wt + 28672;

  ushort* agg1b  = (ushort*)A;
  ushort* agg2b  = (ushort*)A;
  ushort* xb     = (ushort*)B;
  ushort* y2b    = (ushort*)B;
  ushort* h1preb = (ushort*)C;
  ushort* h2preb = (ushort*)E;

  hipMemsetAsync(S, 0, 1024 * sizeof(float), stream);
  hipMemsetAsync(cnt, 0, N_NODES * sizeof(int), stream);

  const int tileBlocks = (N_NODES + 63) / 64;  // 1563

  // independent prep
  cast_bf16<<<(N_NODES * 32 / 4 + 255) / 256, 256, 0, stream>>>(x, xb, N_NODES * 32 / 4);
  wtrans_kernel<<<144, 256, 0, stream>>>(W1rel, W1root, W2rel, W2root, W3rel, W3root, Wt);

  // CSR build (by destination), XCD-affine (R13 structure)
  hist_kernel<<<8 * FILL_SUB, 256, 0, stream>>>(ei, cnt);
  scan_phase1<<<SCAN_NB, 256, 0, stream>>>(cnt, blocksum);
  scan_phase2<<<1, 128, 0, stream>>>(blocksum, rowptr);
  scan_phase3<<<SCAN_NB, 256, 0, stream>>>(cnt, blocksum, rowptr, cursor);
  fill_kernel<<<8 * FILL_SUB, 256, 0, stream>>>(ei, ew, cursor, col);

  // ---- layer 1: h1pre emitted as bf16 only ----
  gather_d32_bf<<<(N_NODES * 4 + 255) / 256, 256, 0, stream>>>(xb, rowptr, col, agg1b);
  gemm_node<32, 32, 64, 1, 1, 0, 0, 0, 1, 1><<<tileBlocks, 256, 0, stream>>>(
      agg1b, xb, Wt1, nullptr, nullptr, nullptr, (float*)h1preb, nullptr, S);
  bn_finalize<<<1, 128, 0, stream>>>(S, g1, be1, S + 128, S + 192, 64);

  // ---- layer 2: gather (BN1 fused) -> agg2b; gemm2 reads agg2b + h1preb (bf16, TA2) ----
  gather_d64_bf<false, true, true><<<(N_NODES * 8 + 255) / 256, 256, 0, stream>>>(
      h1preb, rowptr, col, S + 128, S + 192, agg2b);
  gemm_node<64, 64, 128, 1, 1, 0, 1, 0, 1, 1><<<tileBlocks, 256, 0, stream>>>(
      agg2b, h1preb, Wt2, S + 128, S + 192, nullptr, (float*)h2preb, nullptr, S + 256);
  bn_finalize<<<1, 128, 0, stream>>>(S + 256, g2, be2, S + 512, S + 640, 128);

  // y2b = bf16( relu(bn2(h2preb)) @ W3rel^T )
  gemm_node<128, 0, 64, 1, 0, 1, 0, 0, 0, 1><<<tileBlocks, 256, 0, stream>>>(
      h2preb, nullptr, Wt3r, S + 512, S + 640, nullptr, (float*)y2b, nullptr, nullptr);

  // ---- layer 3 ----
  gather_d64_bf<true, false, false><<<(N_NODES * 8 + 255) / 256, 256, 0, stream>>>(
      y2b, rowptr, col, nullptr, nullptr, A);
  gemm_node<128, 0, 64, 1, 0, 1, 0, 1, 1, 0><<<tileBlocks, 256, 0, stream>>>(
      h2preb, nullptr, Wt3o, S + 512, S + 640, A, B, nullptr, S + 768);
  bn_finalize<<<1, 128, 0, stream>>>(S + 768, g3, be3, S + 896, S + 960, 64);

  // ---- residual + classifier ----
  final_fused<<<tileBlocks, 256, 0, stream>>>(B, h1preb, S + 128, S + 192, S + 896, S + 960,
                                              Wc1, bc1, Wc2, bc2, (float*)d_out);
}